// Round 20
// baseline (3087.012 us; speedup 1.0000x reference)
//
#include <hip/hip_runtime.h>
#include <hip/hip_bf16.h>
#include <math.h>

// Problem dims
#define NB 2048
#define ND 1024
#define NH 8
#define NHD 128
#define NF 4096
#define NL 2
#define NMEM 16
#define NS 17
#define NROWS (NB*NS)      // 34816
#define NTOK 1056          // STO + ACT
#define SCALE_ATT 0.08838834764831845f

typedef unsigned short u16;
typedef unsigned int u32;

typedef __bf16 bf16x8 __attribute__((ext_vector_type(8)));
typedef float f32x4 __attribute__((ext_vector_type(4)));

__device__ __forceinline__ float bf2f(u16 h) {
  union { u32 u; float f; } c; c.u = ((u32)h) << 16; return c.f;
}
__device__ __forceinline__ u16 f2bf(float f) {
  union { float ff; u32 u; } c; c.ff = f;
  return (u16)((c.u + 0x7FFFu + ((c.u >> 16) & 1u)) >> 16);
}
__device__ __forceinline__ bf16x8 as_b8(uint4 u) {
  union { uint4 u; bf16x8 b; } c; c.u = u; return c.b;
}

// async global->LDS 16B (LDS dest = wave base + lane*16)
__device__ __forceinline__ void gload16(const void* g, void* l) {
  __builtin_amdgcn_global_load_lds(
      (const __attribute__((address_space(1))) void*)(uintptr_t)g,
      (__attribute__((address_space(3))) void*)(u32)(uintptr_t)l,
      16, 0, 0);
}

// fast GELU (tanh approx; validated r12/r13: absmax unchanged)
__device__ __forceinline__ float gelu_fast(float x) {
  float u = x * (0.7978845608f + 0.0356774081f * x * x);
  return x * (1.0f / (1.0f + __expf(-2.0f * u)));
}

// ---------------------------------------------------------------------------
// 32x32 transpose-pack core: src f32 [K][N] tile (k0,n0) -> dst bf16 [N][K]
// ---------------------------------------------------------------------------
__device__ __forceinline__ void pack_tile(const float* __restrict__ src,
                                          u16* __restrict__ dst,
                                          int K, int N, int n0, int k0,
                                          float* tile /*[32*33]*/)
{
  int tx = threadIdx.x & 31, ty = threadIdx.x >> 5;  // ty 0..7
#pragma unroll
  for (int r = ty; r < 32; r += 8)
    tile[r * 33 + tx] = src[(size_t)(k0 + r) * N + n0 + tx];
  __syncthreads();
#pragma unroll
  for (int r = ty; r < 32; r += 8)
    dst[(size_t)(n0 + r) * K + k0 + tx] = f2bf(tile[tx * 33 + r]);
}

// standalone pack (input MLP)
__global__ __launch_bounds__(256)
void pack_wT_k(const float* __restrict__ src, u16* __restrict__ dst, int K, int N)
{
  __shared__ float tile[32 * 33];
  pack_tile(src, dst, K, N, blockIdx.x * 32, blockIdx.y * 32, tile);
}

// merged per-layer pack
__global__ __launch_bounds__(256)
void pack_layer_k(const float* __restrict__ wq, const float* __restrict__ wk,
                  const float* __restrict__ wv, const float* __restrict__ wo,
                  const float* __restrict__ w1, const float* __restrict__ w2,
                  const float* __restrict__ bq, const float* __restrict__ bk,
                  const float* __restrict__ bv,
                  u16* __restrict__ qkvT, u16* __restrict__ oT,
                  u16* __restrict__ f1T, u16* __restrict__ f2T,
                  float* __restrict__ BQKV)
{
  __shared__ float tile[32 * 33];
  int id = blockIdx.x;
  if (id < 4096) {
    int which = id >> 10, l = id & 1023;
    const float* src = which == 0 ? wq : which == 1 ? wk : which == 2 ? wv : wo;
    u16* dst = which == 3 ? oT : qkvT + (size_t)which * 1048576;
    pack_tile(src, dst, 1024, 1024, (l & 31) * 32, (l >> 5) * 32, tile);
  } else if (id < 8192) {
    int l = id - 4096;               // f1: K=1024, N=4096
    pack_tile(w1, f1T, 1024, 4096, (l & 127) * 32, (l >> 7) * 32, tile);
  } else if (id < 12288) {
    int l = id - 8192;               // f2: K=4096, N=1024
    pack_tile(w2, f2T, 4096, 1024, (l & 31) * 32, (l >> 5) * 32, tile);
  } else {
    int j = (id - 12288) * 256 + threadIdx.x;
    if (j < 3072)
      BQKV[j] = (j < 1024) ? bq[j] : (j < 2048 ? bk[j - 1024] : bv[j - 2048]);
  }
}

// ---------------------------------------------------------------------------
// GEMM (r13/r16-proven core): A [M,K] bf16 x BT [N,K] bf16 + bias[N] f32.
// 128x128 tile, BK=32, 256 threads (4 waves 2x2), double-buffered LDS,
// global_load_lds w16 prefetch-1-ahead, raw s_barrier, 16B-chunk XOR swizzle.
// Block order: IDENTITY (default round-robin dispatch). All XCDs co-walk the
// same M-row; working set = 1 A-row + full B panel -> L2/L3 resident (weights
// are 2-8 MB). XCD-chunked orders measured 272-367 MB over-fetch here.
// EPI: 0 bf16 store; 1 fast-GELU->bf16; 2 bf16 residual RMW (+=).
// ---------------------------------------------------------------------------
template<int EPI>
__global__ __launch_bounds__(256)
void gemm2_k(const u16* __restrict__ A, int lda,
             const u16* __restrict__ BT, int ldb,
             const float* __restrict__ bias,
             u16* __restrict__ Cb, int ldc,
             int K)
{
  __shared__ __align__(16) u16 Asm[2][128 * 32];
  __shared__ __align__(16) u16 Bsm[2][128 * 32];
  const int tid  = threadIdx.x;
  const int lane = tid & 63;
  const int wv   = tid >> 6;
  const int wm   = wv >> 1, wn = wv & 1;
  const int lr   = lane & 15;
  const int kb   = lane >> 4;

  const int bx = blockIdx.x, by = blockIdx.y;
  const long bmBase = (long)by * 128;
  const int  bnBase = bx * 128;

  const int srow = tid >> 2;
  const int skc  = ((tid & 3) ^ ((srow >> 1) & 3)) * 8;
  const u16* aG0 = A  + (size_t)(bmBase + srow) * lda + skc;
  const u16* aG1 = aG0 + (size_t)64 * lda;
  const u16* bG0 = BT + (size_t)(bnBase + srow) * ldb + skc;
  const u16* bG1 = bG0 + (size_t)64 * ldb;
  const int wbase = (tid & ~63) * 8;
  const int rslot = (kb ^ ((lr >> 1) & 3)) * 8;

  f32x4 acc[4][4];
#pragma unroll
  for (int m = 0; m < 4; ++m)
#pragma unroll
    for (int n = 0; n < 4; ++n)
      acc[m][n] = (f32x4){0.0f, 0.0f, 0.0f, 0.0f};

  const int nk = K >> 5;
  {
    u16* aL = &Asm[0][wbase];
    u16* bL = &Bsm[0][wbase];
    gload16(aG0, aL);
    gload16(aG1, aL + 2048);
    gload16(bG0, bL);
    gload16(bG1, bL + 2048);
  }
  asm volatile("s_waitcnt vmcnt(0)" ::: "memory");
  __builtin_amdgcn_s_barrier();

  for (int i = 0; i < nk; ++i) {
    const int cur = i & 1;
    if (i + 1 < nk) {
      const int kt = (i + 1) << 5;
      u16* aL = &Asm[cur ^ 1][wbase];
      u16* bL = &Bsm[cur ^ 1][wbase];
      gload16(aG0 + kt, aL);
      gload16(aG1 + kt, aL + 2048);
      gload16(bG0 + kt, bL);
      gload16(bG1 + kt, bL + 2048);
    }
    bf16x8 af[4], bfv[4];
#pragma unroll
    for (int m = 0; m < 4; ++m)
      af[m] = as_b8(*(const uint4*)&Asm[cur][(wm * 64 + m * 16 + lr) * 32 + rslot]);
#pragma unroll
    for (int n = 0; n < 4; ++n)
      bfv[n] = as_b8(*(const uint4*)&Bsm[cur][(wn * 64 + n * 16 + lr) * 32 + rslot]);
#pragma unroll
    for (int m = 0; m < 4; ++m)
#pragma unroll
      for (int n = 0; n < 4; ++n)
        acc[m][n] = __builtin_amdgcn_mfma_f32_16x16x32_bf16(af[m], bfv[n], acc[m][n], 0, 0, 0);
    asm volatile("s_waitcnt vmcnt(0)" ::: "memory");
    __builtin_amdgcn_s_barrier();
  }

  // epilogue. C/D layout: col = lane&15, row = (lane>>4)*4 + i
#pragma unroll
  for (int m = 0; m < 4; ++m) {
#pragma unroll
    for (int n = 0; n < 4; ++n) {
      int gcol = bnBase + wn * 64 + n * 16 + lr;
      float bv = bias[gcol];
      long growb = bmBase + wm * 64 + m * 16 + (lane >> 4) * 4;
#pragma unroll
      for (int i = 0; i < 4; ++i) {
        float val = acc[m][n][i] + bv;
        long row = growb + i;
        u16* p = Cb + (size_t)row * ldc + gcol;
        if (EPI == 1) val = gelu_fast(val);
        if (EPI == 2) val += bf2f(*p);
        *p = f2bf(val);
      }
    }
  }
}

// ---------------------------------------------------------------------------
__global__ __launch_bounds__(256)
void prep_tokcat_k(const float* __restrict__ stoch, const float* __restrict__ action,
                   u16* __restrict__ tok)
{
  size_t idx = (size_t)blockIdx.x * 256 + threadIdx.x;
  if (idx >= (size_t)NB * NTOK) return;
  int b = (int)(idx / NTOK), j = (int)(idx % NTOK);
  float v;
  if (j < 1024) {
    v = stoch[(size_t)b * 1024 + j];
  } else {
    float a = action[(size_t)b * 32 + (j - 1024)];
    v = a / fmaxf(fabsf(a), 1.0f);
  }
  tok[idx] = f2bf(v);
}

// ---------------------------------------------------------------------------
// rmsnorm over 1024, bf16 in -> bf16 out. one wave per row, shfl-only reduce.
// ---------------------------------------------------------------------------
__global__ __launch_bounds__(256)
void rmsnorm_bf16_k(const u16* __restrict__ X, const float* __restrict__ w,
                    u16* __restrict__ Y)
{
  const int wv = threadIdx.x >> 6, lane = threadIdx.x & 63;
  const size_t row = (size_t)blockIdx.x * 4 + wv;
  const u16* x = X + row * 1024 + lane * 16;
  union { u16 s[16]; uint4 u[2]; } iv;
  iv.u[0] = ((const uint4*)x)[0];
  iv.u[1] = ((const uint4*)x)[1];
  float f[16];
  float ss = 0.0f;
#pragma unroll
  for (int j = 0; j < 16; ++j) { f[j] = bf2f(iv.s[j]); ss += f[j] * f[j]; }
#pragma unroll
  for (int o = 1; o < 64; o <<= 1) ss += __shfl_xor(ss, o, 64);
  const float r = rsqrtf(ss * (1.0f / 1024.0f) + 1e-4f);
  const float* wp = w + lane * 16;
  union { u16 s[16]; uint4 u[2]; } ob;
#pragma unroll
  for (int j = 0; j < 16; ++j) ob.s[j] = f2bf(f[j] * r * wp[j]);
  uint4* dst = (uint4*)(Y + row * 1024 + lane * 16);
  dst[0] = ob.u[0];
  dst[1] = ob.u[1];
}

// rmsnorm + silu, bf16 in-place, one wave per row
__global__ __launch_bounds__(256)
void rmsnorm_silu_k(u16* __restrict__ X, const float* __restrict__ w)
{
  const int wv = threadIdx.x >> 6, lane = threadIdx.x & 63;
  const size_t row = (size_t)blockIdx.x * 4 + wv;
  u16* x = X + row * 1024 + lane * 16;
  union { u16 s[16]; uint4 u[2]; } iv;
  iv.u[0] = ((const uint4*)x)[0];
  iv.u[1] = ((const uint4*)x)[1];
  float f[16];
  float ss = 0.0f;
#pragma unroll
  for (int j = 0; j < 16; ++j) { f[j] = bf2f(iv.s[j]); ss += f[j] * f[j]; }
#pragma unroll
  for (int o = 1; o < 64; o <<= 1) ss += __shfl_xor(ss, o, 64);
  const float r = rsqrtf(ss * (1.0f / 1024.0f) + 1e-4f);
  const float* wp = w + lane * 16;
  union { u16 s[16]; uint4 u[2]; } ob;
#pragma unroll
  for (int j = 0; j < 16; ++j) {
    float n = f[j] * r * wp[j];
    ob.s[j] = f2bf(n / (1.0f + __expf(-n)));
  }
  ((uint4*)x)[0] = ob.u[0];
  ((uint4*)x)[1] = ob.u[1];
}

// ---------------------------------------------------------------------------
// seq init: seq[b, 0:16, :] = bf16(memory[b])
__global__ __launch_bounds__(256)
void init_seq_k(const float* __restrict__ mem, u16* __restrict__ seq)
{
  size_t idx = ((size_t)blockIdx.x * 256 + threadIdx.x) * 8;
  if (idx >= (size_t)NB * 16 * 1024) return;
  size_t b = idx / (16 * 1024), rem = idx % (16 * 1024);
  float4 v0 = *(const float4*)&mem[idx];
  float4 v1 = *(const float4*)&mem[idx + 4];
  union { u16 s[8]; uint4 u; } ob;
  ob.s[0] = f2bf(v0.x); ob.s[1] = f2bf(v0.y); ob.s[2] = f2bf(v0.z); ob.s[3] = f2bf(v0.w);
  ob.s[4] = f2bf(v1.x); ob.s[5] = f2bf(v1.y); ob.s[6] = f2bf(v1.z); ob.s[7] = f2bf(v1.w);
  *(uint4*)&seq[b * (size_t)NS * 1024 + rem] = ob.u;
}

// new_mem: out f32 = seq[b, 1+i, d] (bf16 -> f32)
__global__ __launch_bounds__(256)
void copy_mem_k(const u16* __restrict__ seq, float* __restrict__ out)
{
  size_t idx = ((size_t)blockIdx.x * 256 + threadIdx.x) * 8;
  if (idx >= (size_t)NB * 16 * 1024) return;
  size_t b = idx / (16 * 1024), rem = idx % (16 * 1024);
  union { u16 s[8]; uint4 u; } iv;
  iv.u = *(const uint4*)&seq[b * (size_t)NS * 1024 + 1024 + rem];
  float4 o0, o1;
  o0.x = bf2f(iv.s[0]); o0.y = bf2f(iv.s[1]); o0.z = bf2f(iv.s[2]); o0.w = bf2f(iv.s[3]);
  o1.x = bf2f(iv.s[4]); o1.y = bf2f(iv.s[5]); o1.z = bf2f(iv.s[6]); o1.w = bf2f(iv.s[7]);
  *(float4*)&out[idx] = o0;
  *(float4*)&out[idx + 4] = o1;
}

// new_deter = rmsnorm(seq[:, 16] + deter, fnw), f32 out
__global__ __launch_bounds__(256)
void final_deter_k(const u16* __restrict__ seq, const float* __restrict__ deter,
                   const float* __restrict__ fnw, float* __restrict__ out)
{
  int b = blockIdx.x;
  const u16* xs = seq + ((size_t)b * NS + 16) * 1024;
  const float* dt = deter + (size_t)b * 1024;
  int t = threadIdx.x;
  union { u16 s[4]; uint2 u; } iv;
  iv.u = *(const uint2*)&xs[t * 4];
  float v[4];
#pragma unroll
  for (int j = 0; j < 4; ++j) v[j] = bf2f(iv.s[j]) + dt[t * 4 + j];
  float ss = v[0] * v[0] + v[1] * v[1] + v[2] * v[2] + v[3] * v[3];
#pragma unroll
  for (int o = 1; o < 64; o <<= 1) ss += __shfl_xor(ss, o, 64);
  __shared__ float red[4];
  if ((t & 63) == 0) red[t >> 6] = ss;
  __syncthreads();
  float tot = red[0] + red[1] + red[2] + red[3];
  float r = rsqrtf(tot * (1.0f / 1024.0f) + 1e-4f);
  float4 ov;
  ov.x = v[0] * r * fnw[t * 4 + 0];
  ov.y = v[1] * r * fnw[t * 4 + 1];
  ov.z = v[2] * r * fnw[t * 4 + 2];
  ov.w = v[3] * r * fnw[t * 4 + 3];
  *(float4*)&out[(size_t)b * 1024 + t * 4] = ov;
}

// ---------------------------------------------------------------------------
// attention: one block per (b, h). S=17, HD=128. QKV fused buffer [B*S][3072].
// ---------------------------------------------------------------------------
#define LSTR 132
__global__ __launch_bounds__(256)
void attn_k(const u16* __restrict__ QKV, const float* __restrict__ rel,
            u16* __restrict__ O)
{
  __shared__ float qs[NS * LSTR];
  __shared__ float ks[NS * LSTR];
  __shared__ float vs[NS * LSTR];
  __shared__ float sc[NS * 20];
  int bh = blockIdx.x;
  int b = bh >> 3, h = bh & 7;
  int t = threadIdx.x;
  const size_t rowb = (size_t)b * NS * 3072 + h * 128;
  for (int e = t; e < NS * 16; e += 256) {
    int i = e >> 4, d = (e & 15) * 8;
    size_t off = rowb + (size_t)i * 3072 + d;
    uint4 q4 = *(const uint4*)(QKV + off);
    uint4 k4 = *(const uint4*)(QKV + off + 1024);
    uint4 v4 = *(const uint4*)(QKV + off + 2048);
    const u16* qp = (const u16*)&q4;
    const u16* kp = (const u16*)&k4;
    const u16* vp = (const u16*)&v4;
#pragma unroll
    for (int j = 0; j < 8; ++j) {
      qs[i * LSTR + d + j] = bf2f(qp[j]);
      ks[i * LSTR + d + j] = bf2f(kp[j]);
      vs[i * LSTR + d + j] = bf2f(vp[j]);
    }
  }
  __syncthreads();
  for (int e = t; e < NS * NS; e += 256) {
    int i = e / NS, j = e % NS;
    const float4* q4 = (const float4*)&qs[i * LSTR];
    const float4* k4 = (const float4*)&ks[j * LSTR];
    float s = 0.0f;
#pragma unroll
    for (int dd = 0; dd < 32; ++dd) {
      float4 a = q4[dd], bb = k4[dd];
      s += a.x * bb.x + a.y * bb.y + a.z * bb.z + a.w * bb.w;
    }
    sc[i * 20 + j] = s * SCALE_ATT + rel[(i - j + 256) * 8 + h];
  }
  __syncthreads();
  if (t < NS) {
    float mx = -1e30f;
    for (int j = 0; j < NS; ++j) mx = fmaxf(mx, sc[t * 20 + j]);
    float sum = 0.0f;
    for (int j = 0; j < NS; ++j) { float e = __expf(sc[t * 20 + j] - mx); sc[t * 20 + j] = e; sum += e; }
    float inv = 1.0f / sum;
    for (int j = 0; j < NS; ++j) sc[t * 20 + j] *= inv;
  }
  __syncthreads();
  const size_t obase = (size_t)b * NS * 1024 + h * 128;
  for (int e = t; e < NS * 128; e += 256) {
    int i = e >> 7, d = e & 127;
    float o = 0.0f;
#pragma unroll
    for (int j = 0; j < NS; ++j) o += sc[i * 20 + j] * vs[j * LSTR + d];
    O[obase + (size_t)i * 1024 + d] = f2bf(o);
  }
}

// ---------------------------------------------------------------------------
extern "C" void kernel_launch(void* const* d_in, const int* in_sizes, int n_in,
                              void* d_out, int out_size, void* d_ws, size_t ws_size,
                              hipStream_t stream)
{
  const float* stoch  = (const float*)d_in[0];
  const float* deter  = (const float*)d_in[1];
  const float* action = (const float*)d_in[2];
  const float* memory = (const float*)d_in[3];
  const float* inp_w1 = (const float*)d_in[4];
  const float* inp_b1 = (const float*)d_in[5];
  const float* inp_nw = (const float*)d_in[6];
  const float* inp_w2 = (const float*)d_in[7];
  const float* inp_b2 = (const float*)d_in[8];
  const float* Wq = (const float*)d_in[9];
  const float* bq = (const float*)d_in[10];
  const float* Wk = (const float*)d_in[11];
  const float* bk = (const float*)d_in[12];
  const float* Wv = (const float*)d_in[13];
  const float* bv = (const float*)d_in[14];
  const float* Wo = (const float*)d_in[15];
  const float* bo = (const float*)d_in[16];
  const float* rel_emb = (const float*)d_in[17];
  const float* n1w = (const float*)d_in[18];
  const float* n2w = (const float*)d_in[19];
  const float* ffw1 = (const float*)d_in[20];
  const float* ffb1 = (const float*)d_in[21];
  const float* ffw2 = (const float*)d_in[22];
  const float* ffb2 = (const float*)d_in[23];
  const float* fnw  = (const float*)d_in[24];
  float* out = (float*)d_out;

  // workspace layout (bytes) — FFH owns the full 285.2 MB region
  char* ws = (char*)d_ws;
  u16* SEQ = (u16*)ws;                                   //  71,303,168
  u16* XN  = (u16*)(ws + 71303168ULL);                   //  71,303,168
  u16* QKV = (u16*)(ws + 142606336ULL);                  // region 285,212,672:
  u16* FFH = QKV;                                        //  QKV 213.9MB, FFH 285.2MB
  u16* TOK = (u16*)(ws + 427819008ULL);                  //   4,325,376
  u16* H1  = (u16*)(ws + 432144384ULL);                  //   4,194,304
  u16* PK  = (u16*)(ws + 436338688ULL);                  //  25,165,824 packed weights
  float* BQKV = (float*)(ws + 461504512ULL);             //      12,288
  if (ws_size < 461516800ULL) return;

  dim3 blk(256);

  // ---- input MLP ----
  u16* w1T = PK;
  u16* w2T = PK + 1024 * 1056;
  pack_wT_k<<<dim3(1024 / 32, 1056 / 32), blk, 0, stream>>>(inp_w1, w1T, NTOK, 1024);
  pack_wT_k<<<dim3(1024 / 32, 1024 / 32), blk, 0, stream>>>(inp_w2, w2T, 1024, 1024);
  prep_tokcat_k<<<(NB * NTOK + 255) / 256, blk, 0, stream>>>(stoch, action, TOK);
  gemm2_k<0><<<dim3(8, 16), blk, 0, stream>>>(TOK, NTOK, w1T, NTOK, inp_b1, H1, 1024, NTOK);
  rmsnorm_silu_k<<<NB / 4, blk, 0, stream>>>(H1, inp_nw);
  gemm2_k<0><<<dim3(8, 16), blk, 0, stream>>>(H1, 1024, w2T, 1024, inp_b2, SEQ + 16 * 1024, NS * 1024, 1024);
  init_seq_k<<<(NB * 16 * 1024 / 8 + 255) / 256, blk, 0, stream>>>(memory, SEQ);

  // packed per-layer weight slots (qkvT contiguous = [3072][1024])
  u16* qkvT = PK;
  u16* oT  = PK + 3145728;
  u16* f1T = PK + 4194304;   // [4096][1024]
  u16* f2T = PK + 8388608;   // [1024][4096]

  for (int l = 0; l < NL; ++l) {
    const float* wq = Wq + (size_t)l * ND * ND;
    const float* wk = Wk + (size_t)l * ND * ND;
    const float* wv = Wv + (size_t)l * ND * ND;
    const float* wo = Wo + (size_t)l * ND * ND;
    const float* w1 = ffw1 + (size_t)l * ND * NF;
    const float* w2 = ffw2 + (size_t)l * NF * ND;
    const float* rl = rel_emb + (size_t)l * 513 * NH;

    pack_layer_k<<<12300, blk, 0, stream>>>(wq, wk, wv, wo, w1, w2,
                                            bq + l * ND, bk + l * ND, bv + l * ND,
                                            qkvT, oT, f1T, f2T, BQKV);

    rmsnorm_bf16_k<<<NROWS / 4, blk, 0, stream>>>(SEQ, n1w + l * ND, XN);
    gemm2_k<0><<<dim3(24, 272), blk, 0, stream>>>(XN, 1024, qkvT, 1024, BQKV, QKV, 3072, 1024);
    attn_k<<<NB * NH, blk, 0, stream>>>(QKV, rl, XN);
    gemm2_k<2><<<dim3(8, 272), blk, 0, stream>>>(XN, 1024, oT, 1024, bo + l * ND, SEQ, 1024, 1024);
    rmsnorm_bf16_k<<<NROWS / 4, blk, 0, stream>>>(SEQ, n2w + l * ND, XN);
    gemm2_k<1><<<dim3(32, 272), blk, 0, stream>>>(XN, 1024, f1T, 1024, ffb1 + l * NF, FFH, 4096, 1024);
    gemm2_k<2><<<dim3(8, 272), blk, 0, stream>>>(FFH, 4096, f2T, 4096, ffb2 + l * ND, SEQ, 1024, 4096);
  }

  final_deter_k<<<NB, blk, 0, stream>>>(SEQ, deter, fnw, out);
  copy_mem_k<<<(NB * 16 * 1024 / 8 + 255) / 256, blk, 0, stream>>>(SEQ, out + (size_t)NB * ND);
}

// Round 21
// 2913.715 us; speedup vs baseline: 1.0595x; 1.0595x over previous
//
#include <hip/hip_runtime.h>
#include <hip/hip_bf16.h>
#include <math.h>

// Problem dims
#define NB 2048
#define ND 1024
#define NH 8
#define NHD 128
#define NF 4096
#define NL 2
#define NMEM 16
#define NS 17
#define NROWS (NB*NS)      // 34816
#define NTOK 1056          // STO + ACT
#define SCALE_ATT 0.08838834764831845f

typedef unsigned short u16;
typedef unsigned int u32;

typedef __bf16 bf16x8 __attribute__((ext_vector_type(8)));
typedef float f32x4 __attribute__((ext_vector_type(4)));

__device__ __forceinline__ float bf2f(u16 h) {
  union { u32 u; float f; } c; c.u = ((u32)h) << 16; return c.f;
}
__device__ __forceinline__ u16 f2bf(float f) {
  union { float ff; u32 u; } c; c.ff = f;
  return (u16)((c.u + 0x7FFFu + ((c.u >> 16) & 1u)) >> 16);
}
__device__ __forceinline__ bf16x8 as_b8(uint4 u) {
  union { uint4 u; bf16x8 b; } c; c.u = u; return c.b;
}

// async global->LDS 16B (LDS dest = wave base + lane*16)
__device__ __forceinline__ void gload16(const void* g, void* l) {
  __builtin_amdgcn_global_load_lds(
      (const __attribute__((address_space(1))) void*)(uintptr_t)g,
      (__attribute__((address_space(3))) void*)(u32)(uintptr_t)l,
      16, 0, 0);
}

// fast GELU (tanh approx; validated r12/r13: absmax unchanged)
__device__ __forceinline__ float gelu_fast(float x) {
  float u = x * (0.7978845608f + 0.0356774081f * x * x);
  return x * (1.0f / (1.0f + __expf(-2.0f * u)));
}

// ---------------------------------------------------------------------------
// 32x32 transpose-pack core: src f32 [K][N] tile (k0,n0) -> dst bf16 [N][K]
// ---------------------------------------------------------------------------
__device__ __forceinline__ void pack_tile(const float* __restrict__ src,
                                          u16* __restrict__ dst,
                                          int K, int N, int n0, int k0,
                                          float* tile /*[32*33]*/)
{
  int tx = threadIdx.x & 31, ty = threadIdx.x >> 5;  // ty 0..7
#pragma unroll
  for (int r = ty; r < 32; r += 8)
    tile[r * 33 + tx] = src[(size_t)(k0 + r) * N + n0 + tx];
  __syncthreads();
#pragma unroll
  for (int r = ty; r < 32; r += 8)
    dst[(size_t)(n0 + r) * K + k0 + tx] = f2bf(tile[tx * 33 + r]);
}

// standalone pack (input MLP)
__global__ __launch_bounds__(256)
void pack_wT_k(const float* __restrict__ src, u16* __restrict__ dst, int K, int N)
{
  __shared__ float tile[32 * 33];
  pack_tile(src, dst, K, N, blockIdx.x * 32, blockIdx.y * 32, tile);
}

// merged per-layer pack
__global__ __launch_bounds__(256)
void pack_layer_k(const float* __restrict__ wq, const float* __restrict__ wk,
                  const float* __restrict__ wv, const float* __restrict__ wo,
                  const float* __restrict__ w1, const float* __restrict__ w2,
                  const float* __restrict__ bq, const float* __restrict__ bk,
                  const float* __restrict__ bv,
                  u16* __restrict__ qkvT, u16* __restrict__ oT,
                  u16* __restrict__ f1T, u16* __restrict__ f2T,
                  float* __restrict__ BQKV)
{
  __shared__ float tile[32 * 33];
  int id = blockIdx.x;
  if (id < 4096) {
    int which = id >> 10, l = id & 1023;
    const float* src = which == 0 ? wq : which == 1 ? wk : which == 2 ? wv : wo;
    u16* dst = which == 3 ? oT : qkvT + (size_t)which * 1048576;
    pack_tile(src, dst, 1024, 1024, (l & 31) * 32, (l >> 5) * 32, tile);
  } else if (id < 8192) {
    int l = id - 4096;               // f1: K=1024, N=4096
    pack_tile(w1, f1T, 1024, 4096, (l & 127) * 32, (l >> 7) * 32, tile);
  } else if (id < 12288) {
    int l = id - 8192;               // f2: K=4096, N=1024
    pack_tile(w2, f2T, 4096, 1024, (l & 31) * 32, (l >> 5) * 32, tile);
  } else {
    int j = (id - 12288) * 256 + threadIdx.x;
    if (j < 3072)
      BQKV[j] = (j < 1024) ? bq[j] : (j < 2048 ? bk[j - 1024] : bv[j - 2048]);
  }
}

// ---------------------------------------------------------------------------
// GEMM (r13/r16-proven core): A [M,K] bf16 x BT [N,K] bf16 + bias[N] f32.
// 128x128 tile, BK=32, 256 threads (4 waves 2x2), double-buffered LDS,
// global_load_lds w16 prefetch-1-ahead, raw s_barrier, 16B-chunk XOR swizzle.
// Grouped XCD traversal (r19, best of 3 measured orders): each XCD walks
// M-fast within a GN-wide group of N-columns (GN B-panels stay L2-resident).
// Requires nwg%8==0 and gridDim.x%GN==0.
// EPI: 0 bf16 store; 1 fast-GELU->bf16; 2 bf16 residual RMW (+=).
// ---------------------------------------------------------------------------
template<int EPI>
__global__ __launch_bounds__(256)
void gemm2_k(const u16* __restrict__ A, int lda,
             const u16* __restrict__ BT, int ldb,
             const float* __restrict__ bias,
             u16* __restrict__ Cb, int ldc,
             int K, int GN)
{
  __shared__ __align__(16) u16 Asm[2][128 * 32];
  __shared__ __align__(16) u16 Bsm[2][128 * 32];
  const int tid  = threadIdx.x;
  const int lane = tid & 63;
  const int wv   = tid >> 6;
  const int wm   = wv >> 1, wn = wv & 1;
  const int lr   = lane & 15;
  const int kb   = lane >> 4;

  const int gx = gridDim.x, gy = gridDim.y;
  const int nwg = gx * gy;
  int h = blockIdx.y * gx + blockIdx.x;
  // contiguous chunk per XCD, then (group, by, bxin) decode: M-fast in group
  int s = (h & 7) * (nwg >> 3) + (h >> 3);
  const int gsz = gy * GN;
  int g = s / gsz;
  int rem = s - g * gsz;
  int by = rem / GN;
  int bx = g * GN + (rem - by * GN);
  const long bmBase = (long)by * 128;
  const int  bnBase = bx * 128;

  const int srow = tid >> 2;
  const int skc  = ((tid & 3) ^ ((srow >> 1) & 3)) * 8;
  const u16* aG0 = A  + (size_t)(bmBase + srow) * lda + skc;
  const u16* aG1 = aG0 + (size_t)64 * lda;
  const u16* bG0 = BT + (size_t)(bnBase + srow) * ldb + skc;
  const u16* bG1 = bG0 + (size_t)64 * ldb;
  const int wbase = (tid & ~63) * 8;
  const int rslot = (kb ^ ((lr >> 1) & 3)) * 8;

  f32x4 acc[4][4];
#pragma unroll
  for (int m = 0; m < 4; ++m)
#pragma unroll
    for (int n = 0; n < 4; ++n)
      acc[m][n] = (f32x4){0.0f, 0.0f, 0.0f, 0.0f};

  const int nk = K >> 5;
  {
    u16* aL = &Asm[0][wbase];
    u16* bL = &Bsm[0][wbase];
    gload16(aG0, aL);
    gload16(aG1, aL + 2048);
    gload16(bG0, bL);
    gload16(bG1, bL + 2048);
  }
  asm volatile("s_waitcnt vmcnt(0)" ::: "memory");
  __builtin_amdgcn_s_barrier();

  for (int i = 0; i < nk; ++i) {
    const int cur = i & 1;
    if (i + 1 < nk) {
      const int kt = (i + 1) << 5;
      u16* aL = &Asm[cur ^ 1][wbase];
      u16* bL = &Bsm[cur ^ 1][wbase];
      gload16(aG0 + kt, aL);
      gload16(aG1 + kt, aL + 2048);
      gload16(bG0 + kt, bL);
      gload16(bG1 + kt, bL + 2048);
    }
    bf16x8 af[4], bfv[4];
#pragma unroll
    for (int m = 0; m < 4; ++m)
      af[m] = as_b8(*(const uint4*)&Asm[cur][(wm * 64 + m * 16 + lr) * 32 + rslot]);
#pragma unroll
    for (int n = 0; n < 4; ++n)
      bfv[n] = as_b8(*(const uint4*)&Bsm[cur][(wn * 64 + n * 16 + lr) * 32 + rslot]);
#pragma unroll
    for (int m = 0; m < 4; ++m)
#pragma unroll
      for (int n = 0; n < 4; ++n)
        acc[m][n] = __builtin_amdgcn_mfma_f32_16x16x32_bf16(af[m], bfv[n], acc[m][n], 0, 0, 0);
    asm volatile("s_waitcnt vmcnt(0)" ::: "memory");
    __builtin_amdgcn_s_barrier();
  }

  // epilogue. C/D layout: col = lane&15, row = (lane>>4)*4 + i
#pragma unroll
  for (int m = 0; m < 4; ++m) {
#pragma unroll
    for (int n = 0; n < 4; ++n) {
      int gcol = bnBase + wn * 64 + n * 16 + lr;
      float bv = bias[gcol];
      long growb = bmBase + wm * 64 + m * 16 + (lane >> 4) * 4;
#pragma unroll
      for (int i = 0; i < 4; ++i) {
        float val = acc[m][n][i] + bv;
        long row = growb + i;
        u16* p = Cb + (size_t)row * ldc + gcol;
        if (EPI == 1) val = gelu_fast(val);
        if (EPI == 2) val += bf2f(*p);
        *p = f2bf(val);
      }
    }
  }
}

// ---------------------------------------------------------------------------
__global__ __launch_bounds__(256)
void prep_tokcat_k(const float* __restrict__ stoch, const float* __restrict__ action,
                   u16* __restrict__ tok)
{
  size_t idx = (size_t)blockIdx.x * 256 + threadIdx.x;
  if (idx >= (size_t)NB * NTOK) return;
  int b = (int)(idx / NTOK), j = (int)(idx % NTOK);
  float v;
  if (j < 1024) {
    v = stoch[(size_t)b * 1024 + j];
  } else {
    float a = action[(size_t)b * 32 + (j - 1024)];
    v = a / fmaxf(fabsf(a), 1.0f);
  }
  tok[idx] = f2bf(v);
}

// ---------------------------------------------------------------------------
// rmsnorm over 1024, bf16 in -> bf16 out. one wave per row, shfl-only reduce.
// ---------------------------------------------------------------------------
__global__ __launch_bounds__(256)
void rmsnorm_bf16_k(const u16* __restrict__ X, const float* __restrict__ w,
                    u16* __restrict__ Y)
{
  const int wv = threadIdx.x >> 6, lane = threadIdx.x & 63;
  const size_t row = (size_t)blockIdx.x * 4 + wv;
  const u16* x = X + row * 1024 + lane * 16;
  union { u16 s[16]; uint4 u[2]; } iv;
  iv.u[0] = ((const uint4*)x)[0];
  iv.u[1] = ((const uint4*)x)[1];
  float f[16];
  float ss = 0.0f;
#pragma unroll
  for (int j = 0; j < 16; ++j) { f[j] = bf2f(iv.s[j]); ss += f[j] * f[j]; }
#pragma unroll
  for (int o = 1; o < 64; o <<= 1) ss += __shfl_xor(ss, o, 64);
  const float r = rsqrtf(ss * (1.0f / 1024.0f) + 1e-4f);
  const float* wp = w + lane * 16;
  union { u16 s[16]; uint4 u[2]; } ob;
#pragma unroll
  for (int j = 0; j < 16; ++j) ob.s[j] = f2bf(f[j] * r * wp[j]);
  uint4* dst = (uint4*)(Y + row * 1024 + lane * 16);
  dst[0] = ob.u[0];
  dst[1] = ob.u[1];
}

// rmsnorm + silu, bf16 in-place, one wave per row
__global__ __launch_bounds__(256)
void rmsnorm_silu_k(u16* __restrict__ X, const float* __restrict__ w)
{
  const int wv = threadIdx.x >> 6, lane = threadIdx.x & 63;
  const size_t row = (size_t)blockIdx.x * 4 + wv;
  u16* x = X + row * 1024 + lane * 16;
  union { u16 s[16]; uint4 u[2]; } iv;
  iv.u[0] = ((const uint4*)x)[0];
  iv.u[1] = ((const uint4*)x)[1];
  float f[16];
  float ss = 0.0f;
#pragma unroll
  for (int j = 0; j < 16; ++j) { f[j] = bf2f(iv.s[j]); ss += f[j] * f[j]; }
#pragma unroll
  for (int o = 1; o < 64; o <<= 1) ss += __shfl_xor(ss, o, 64);
  const float r = rsqrtf(ss * (1.0f / 1024.0f) + 1e-4f);
  const float* wp = w + lane * 16;
  union { u16 s[16]; uint4 u[2]; } ob;
#pragma unroll
  for (int j = 0; j < 16; ++j) {
    float n = f[j] * r * wp[j];
    ob.s[j] = f2bf(n / (1.0f + __expf(-n)));
  }
  ((uint4*)x)[0] = ob.u[0];
  ((uint4*)x)[1] = ob.u[1];
}

// ---------------------------------------------------------------------------
// seq init: seq[b, 0:16, :] = bf16(memory[b])
__global__ __launch_bounds__(256)
void init_seq_k(const float* __restrict__ mem, u16* __restrict__ seq)
{
  size_t idx = ((size_t)blockIdx.x * 256 + threadIdx.x) * 8;
  if (idx >= (size_t)NB * 16 * 1024) return;
  size_t b = idx / (16 * 1024), rem = idx % (16 * 1024);
  float4 v0 = *(const float4*)&mem[idx];
  float4 v1 = *(const float4*)&mem[idx + 4];
  union { u16 s[8]; uint4 u; } ob;
  ob.s[0] = f2bf(v0.x); ob.s[1] = f2bf(v0.y); ob.s[2] = f2bf(v0.z); ob.s[3] = f2bf(v0.w);
  ob.s[4] = f2bf(v1.x); ob.s[5] = f2bf(v1.y); ob.s[6] = f2bf(v1.z); ob.s[7] = f2bf(v1.w);
  *(uint4*)&seq[b * (size_t)NS * 1024 + rem] = ob.u;
}

// new_mem: out f32 = seq[b, 1+i, d] (bf16 -> f32)
__global__ __launch_bounds__(256)
void copy_mem_k(const u16* __restrict__ seq, float* __restrict__ out)
{
  size_t idx = ((size_t)blockIdx.x * 256 + threadIdx.x) * 8;
  if (idx >= (size_t)NB * 16 * 1024) return;
  size_t b = idx / (16 * 1024), rem = idx % (16 * 1024);
  union { u16 s[8]; uint4 u; } iv;
  iv.u = *(const uint4*)&seq[b * (size_t)NS * 1024 + 1024 + rem];
  float4 o0, o1;
  o0.x = bf2f(iv.s[0]); o0.y = bf2f(iv.s[1]); o0.z = bf2f(iv.s[2]); o0.w = bf2f(iv.s[3]);
  o1.x = bf2f(iv.s[4]); o1.y = bf2f(iv.s[5]); o1.z = bf2f(iv.s[6]); o1.w = bf2f(iv.s[7]);
  *(float4*)&out[idx] = o0;
  *(float4*)&out[idx + 4] = o1;
}

// new_deter = rmsnorm(seq[:, 16] + deter, fnw), f32 out
__global__ __launch_bounds__(256)
void final_deter_k(const u16* __restrict__ seq, const float* __restrict__ deter,
                   const float* __restrict__ fnw, float* __restrict__ out)
{
  int b = blockIdx.x;
  const u16* xs = seq + ((size_t)b * NS + 16) * 1024;
  const float* dt = deter + (size_t)b * 1024;
  int t = threadIdx.x;
  union { u16 s[4]; uint2 u; } iv;
  iv.u = *(const uint2*)&xs[t * 4];
  float v[4];
#pragma unroll
  for (int j = 0; j < 4; ++j) v[j] = bf2f(iv.s[j]) + dt[t * 4 + j];
  float ss = v[0] * v[0] + v[1] * v[1] + v[2] * v[2] + v[3] * v[3];
#pragma unroll
  for (int o = 1; o < 64; o <<= 1) ss += __shfl_xor(ss, o, 64);
  __shared__ float red[4];
  if ((t & 63) == 0) red[t >> 6] = ss;
  __syncthreads();
  float tot = red[0] + red[1] + red[2] + red[3];
  float r = rsqrtf(tot * (1.0f / 1024.0f) + 1e-4f);
  float4 ov;
  ov.x = v[0] * r * fnw[t * 4 + 0];
  ov.y = v[1] * r * fnw[t * 4 + 1];
  ov.z = v[2] * r * fnw[t * 4 + 2];
  ov.w = v[3] * r * fnw[t * 4 + 3];
  *(float4*)&out[(size_t)b * 1024 + t * 4] = ov;
}

// ---------------------------------------------------------------------------
// attention: one block per (b, h). S=17, HD=128. QKV fused buffer [B*S][3072].
// ---------------------------------------------------------------------------
#define LSTR 132
__global__ __launch_bounds__(256)
void attn_k(const u16* __restrict__ QKV, const float* __restrict__ rel,
            u16* __restrict__ O)
{
  __shared__ float qs[NS * LSTR];
  __shared__ float ks[NS * LSTR];
  __shared__ float vs[NS * LSTR];
  __shared__ float sc[NS * 20];
  int bh = blockIdx.x;
  int b = bh >> 3, h = bh & 7;
  int t = threadIdx.x;
  const size_t rowb = (size_t)b * NS * 3072 + h * 128;
  for (int e = t; e < NS * 16; e += 256) {
    int i = e >> 4, d = (e & 15) * 8;
    size_t off = rowb + (size_t)i * 3072 + d;
    uint4 q4 = *(const uint4*)(QKV + off);
    uint4 k4 = *(const uint4*)(QKV + off + 1024);
    uint4 v4 = *(const uint4*)(QKV + off + 2048);
    const u16* qp = (const u16*)&q4;
    const u16* kp = (const u16*)&k4;
    const u16* vp = (const u16*)&v4;
#pragma unroll
    for (int j = 0; j < 8; ++j) {
      qs[i * LSTR + d + j] = bf2f(qp[j]);
      ks[i * LSTR + d + j] = bf2f(kp[j]);
      vs[i * LSTR + d + j] = bf2f(vp[j]);
    }
  }
  __syncthreads();
  for (int e = t; e < NS * NS; e += 256) {
    int i = e / NS, j = e % NS;
    const float4* q4 = (const float4*)&qs[i * LSTR];
    const float4* k4 = (const float4*)&ks[j * LSTR];
    float s = 0.0f;
#pragma unroll
    for (int dd = 0; dd < 32; ++dd) {
      float4 a = q4[dd], bb = k4[dd];
      s += a.x * bb.x + a.y * bb.y + a.z * bb.z + a.w * bb.w;
    }
    sc[i * 20 + j] = s * SCALE_ATT + rel[(i - j + 256) * 8 + h];
  }
  __syncthreads();
  if (t < NS) {
    float mx = -1e30f;
    for (int j = 0; j < NS; ++j) mx = fmaxf(mx, sc[t * 20 + j]);
    float sum = 0.0f;
    for (int j = 0; j < NS; ++j) { float e = __expf(sc[t * 20 + j] - mx); sc[t * 20 + j] = e; sum += e; }
    float inv = 1.0f / sum;
    for (int j = 0; j < NS; ++j) sc[t * 20 + j] *= inv;
  }
  __syncthreads();
  const size_t obase = (size_t)b * NS * 1024 + h * 128;
  for (int e = t; e < NS * 128; e += 256) {
    int i = e >> 7, d = e & 127;
    float o = 0.0f;
#pragma unroll
    for (int j = 0; j < NS; ++j) o += sc[i * 20 + j] * vs[j * LSTR + d];
    O[obase + (size_t)i * 1024 + d] = f2bf(o);
  }
}

// ---------------------------------------------------------------------------
extern "C" void kernel_launch(void* const* d_in, const int* in_sizes, int n_in,
                              void* d_out, int out_size, void* d_ws, size_t ws_size,
                              hipStream_t stream)
{
  const float* stoch  = (const float*)d_in[0];
  const float* deter  = (const float*)d_in[1];
  const float* action = (const float*)d_in[2];
  const float* memory = (const float*)d_in[3];
  const float* inp_w1 = (const float*)d_in[4];
  const float* inp_b1 = (const float*)d_in[5];
  const float* inp_nw = (const float*)d_in[6];
  const float* inp_w2 = (const float*)d_in[7];
  const float* inp_b2 = (const float*)d_in[8];
  const float* Wq = (const float*)d_in[9];
  const float* bq = (const float*)d_in[10];
  const float* Wk = (const float*)d_in[11];
  const float* bk = (const float*)d_in[12];
  const float* Wv = (const float*)d_in[13];
  const float* bv = (const float*)d_in[14];
  const float* Wo = (const float*)d_in[15];
  const float* bo = (const float*)d_in[16];
  const float* rel_emb = (const float*)d_in[17];
  const float* n1w = (const float*)d_in[18];
  const float* n2w = (const float*)d_in[19];
  const float* ffw1 = (const float*)d_in[20];
  const float* ffb1 = (const float*)d_in[21];
  const float* ffw2 = (const float*)d_in[22];
  const float* ffb2 = (const float*)d_in[23];
  const float* fnw  = (const float*)d_in[24];
  float* out = (float*)d_out;

  // workspace layout (bytes) — FFH owns the full 285.2 MB region
  char* ws = (char*)d_ws;
  u16* SEQ = (u16*)ws;                                   //  71,303,168
  u16* XN  = (u16*)(ws + 71303168ULL);                   //  71,303,168
  u16* QKV = (u16*)(ws + 142606336ULL);                  // region 285,212,672:
  u16* FFH = QKV;                                        //  QKV 213.9MB, FFH 285.2MB
  u16* TOK = (u16*)(ws + 427819008ULL);                  //   4,325,376
  u16* H1  = (u16*)(ws + 432144384ULL);                  //   4,194,304
  u16* PK  = (u16*)(ws + 436338688ULL);                  //  25,165,824 packed weights
  float* BQKV = (float*)(ws + 461504512ULL);             //      12,288
  if (ws_size < 461516800ULL) return;

  dim3 blk(256);

  // ---- input MLP ----
  u16* w1T = PK;
  u16* w2T = PK + 1024 * 1056;
  pack_wT_k<<<dim3(1024 / 32, 1056 / 32), blk, 0, stream>>>(inp_w1, w1T, NTOK, 1024);
  pack_wT_k<<<dim3(1024 / 32, 1024 / 32), blk, 0, stream>>>(inp_w2, w2T, 1024, 1024);
  prep_tokcat_k<<<(NB * NTOK + 255) / 256, blk, 0, stream>>>(stoch, action, TOK);
  gemm2_k<0><<<dim3(8, 16), blk, 0, stream>>>(TOK, NTOK, w1T, NTOK, inp_b1, H1, 1024, NTOK, 8);
  rmsnorm_silu_k<<<NB / 4, blk, 0, stream>>>(H1, inp_nw);
  gemm2_k<0><<<dim3(8, 16), blk, 0, stream>>>(H1, 1024, w2T, 1024, inp_b2, SEQ + 16 * 1024, NS * 1024, 1024, 8);
  init_seq_k<<<(NB * 16 * 1024 / 8 + 255) / 256, blk, 0, stream>>>(memory, SEQ);

  // packed per-layer weight slots (qkvT contiguous = [3072][1024])
  u16* qkvT = PK;
  u16* oT  = PK + 3145728;
  u16* f1T = PK + 4194304;   // [4096][1024]
  u16* f2T = PK + 8388608;   // [1024][4096]

  for (int l = 0; l < NL; ++l) {
    const float* wq = Wq + (size_t)l * ND * ND;
    const float* wk = Wk + (size_t)l * ND * ND;
    const float* wv = Wv + (size_t)l * ND * ND;
    const float* wo = Wo + (size_t)l * ND * ND;
    const float* w1 = ffw1 + (size_t)l * ND * NF;
    const float* w2 = ffw2 + (size_t)l * NF * ND;
    const float* rl = rel_emb + (size_t)l * 513 * NH;

    pack_layer_k<<<12300, blk, 0, stream>>>(wq, wk, wv, wo, w1, w2,
                                            bq + l * ND, bk + l * ND, bv + l * ND,
                                            qkvT, oT, f1T, f2T, BQKV);

    rmsnorm_bf16_k<<<NROWS / 4, blk, 0, stream>>>(SEQ, n1w + l * ND, XN);
    gemm2_k<0><<<dim3(24, 272), blk, 0, stream>>>(XN, 1024, qkvT, 1024, BQKV, QKV, 3072, 1024, 8);
    attn_k<<<NB * NH, blk, 0, stream>>>(QKV, rl, XN);
    gemm2_k<2><<<dim3(8, 272), blk, 0, stream>>>(XN, 1024, oT, 1024, bo + l * ND, SEQ, 1024, 1024, 8);
    rmsnorm_bf16_k<<<NROWS / 4, blk, 0, stream>>>(SEQ, n2w + l * ND, XN);
    gemm2_k<1><<<dim3(32, 272), blk, 0, stream>>>(XN, 1024, f1T, 1024, ffb1 + l * NF, FFH, 4096, 1024, 8);
    gemm2_k<2><<<dim3(8, 272), blk, 0, stream>>>(FFH, 4096, f2T, 4096, ffb2 + l * ND, SEQ, 1024, 4096, 4);
  }

  final_deter_k<<<NB, blk, 0, stream>>>(SEQ, deter, fnw, out);
  copy_mem_k<<<(NB * 16 * 1024 / 8 + 255) / 256, blk, 0, stream>>>(SEQ, out + (size_t)NB * ND);
}